// Round 11
// baseline (435.289 us; speedup 1.0000x reference)
//
#include <hip/hip_runtime.h>

typedef unsigned short u16;
typedef __attribute__((ext_vector_type(8))) short short8;
typedef __attribute__((ext_vector_type(4))) unsigned short u16x4;
typedef __attribute__((ext_vector_type(4))) float f32x4;

#define DEV __device__ __forceinline__
#define VMW(n) asm volatile("s_waitcnt vmcnt(" #n ")" ::: "memory")

DEV float bf2f(u16 u) { return __uint_as_float(((unsigned int)u) << 16); }
DEV u16 f2bf(float f) {
  unsigned int u = __float_as_uint(f);
  u += 0x7FFF + ((u >> 16) & 1);
  return (u16)(u >> 16);
}

DEV float redmax16(float v) {
  v = fmaxf(v, __shfl_xor(v, 1));
  v = fmaxf(v, __shfl_xor(v, 2));
  v = fmaxf(v, __shfl_xor(v, 4));
  v = fmaxf(v, __shfl_xor(v, 8));
  return v;
}
DEV float redsum16(float v) {
  v += __shfl_xor(v, 1);
  v += __shfl_xor(v, 2);
  v += __shfl_xor(v, 4);
  v += __shfl_xor(v, 8);
  return v;
}

// ---------------- transpose + cast f32 -> bf16, 32x32 tiles ----------------
__global__ __launch_bounds__(256) void transpose_f32_bf16(const float* __restrict__ in,
                                                          u16* __restrict__ out,
                                                          int R, int C) {
  __shared__ u16 tile[32][33];
  int tx = threadIdx.x & 31, ty = threadIdx.x >> 5;  // 32 x 8
  int r0 = blockIdx.y * 32, c0 = blockIdx.x * 32;
#pragma unroll
  for (int i = 0; i < 32; i += 8)
    tile[ty + i][tx] = f2bf(in[(size_t)(r0 + ty + i) * C + c0 + tx]);
  __syncthreads();
#pragma unroll
  for (int i = 0; i < 32; i += 8)
    out[(size_t)(c0 + ty + i) * R + r0 + tx] = tile[tx][ty + i];
}

// ---------------- transpose V third of qkv -> vT[b,h][64][4096] -------------
__global__ __launch_bounds__(256) void transpose_v(const u16* __restrict__ qkv,
                                                   u16* __restrict__ vT) {
  __shared__ u16 tile[32][33];
  int tx = threadIdx.x & 31, ty = threadIdx.x >> 5;  // 32 x 8
  int s0 = blockIdx.x * 32, d0 = blockIdx.y * 32;
  int bh = blockIdx.z;
  const u16* src = qkv + (size_t)(bh >> 4) * 4096 * 3072 + 2048 + (bh & 15) * 64;
#pragma unroll
  for (int i = 0; i < 32; i += 8)
    tile[ty + i][tx] = src[(size_t)(s0 + ty + i) * 3072 + d0 + tx];
  __syncthreads();
  u16* dst = vT + (size_t)bh * 64 * 4096;
#pragma unroll
  for (int i = 0; i < 32; i += 8)
    dst[(size_t)(d0 + ty + i) * 4096 + s0 + tx] = tile[tx][ty + i];
}

// ---------------- RMSNorm: 8192 rows x 1024, f32 in -> bf16 out ----------------
__global__ __launch_bounds__(256) void rmsnorm_kernel(const float* __restrict__ x,
                                                      const float* __restrict__ w,
                                                      u16* __restrict__ xn) {
  int row = blockIdx.x, t = threadIdx.x;
  const float4* xr = reinterpret_cast<const float4*>(x + (size_t)row * 1024);
  float4 v = xr[t];
  float ss = v.x * v.x + v.y * v.y + v.z * v.z + v.w * v.w;
#pragma unroll
  for (int d = 1; d < 64; d <<= 1) ss += __shfl_xor(ss, d);
  __shared__ float red[4];
  if ((t & 63) == 0) red[t >> 6] = ss;
  __syncthreads();
  float tot = red[0] + red[1] + red[2] + red[3];
  float inv = rsqrtf(tot * (1.0f / 1024.0f) + 1e-6f);
  float4 wv = reinterpret_cast<const float4*>(w)[t];
  u16x4 o;
  o[0] = f2bf(v.x * inv * wv.x);
  o[1] = f2bf(v.y * inv * wv.y);
  o[2] = f2bf(v.z * inv * wv.z);
  o[3] = f2bf(v.w * inv * wv.w);
  *reinterpret_cast<u16x4*>(xn + (size_t)row * 1024 + t * 4) = o;
}

// ------- RoPE in-place, vectorized: one block per qkv row; q scaled 0.125 ----
__global__ __launch_bounds__(256) void rope_kernel(u16* __restrict__ qkv,
                                                   const float* __restrict__ sp,
                                                   const float* __restrict__ cp) {
  int row = blockIdx.x;  // 8192 rows
  int t = threadIdx.x;
  int pos = row & 4095;
  int e0 = t * 8;
  float sc = (e0 < 1024) ? 0.125f : 1.0f;  // fold 1/sqrt(64) into q (exact)
  int d0 = e0 & 63;
  u16* p = qkv + (size_t)row * 3072 + e0;
  short8 v = *reinterpret_cast<const short8*>(p);
  float4 s01 = *reinterpret_cast<const float4*>(sp + pos * 64 + d0);
  float4 s23 = *reinterpret_cast<const float4*>(sp + pos * 64 + d0 + 4);
  float4 c01 = *reinterpret_cast<const float4*>(cp + pos * 64 + d0);
  float4 c23 = *reinterpret_cast<const float4*>(cp + pos * 64 + d0 + 4);
  short8 o;
  float xe, xo;
  xe = bf2f((u16)v[0]); xo = bf2f((u16)v[1]);
  o[0] = (short)f2bf((xe * c01.x - xo * s01.x) * sc);
  o[1] = (short)f2bf((xo * c01.y + xe * s01.y) * sc);
  xe = bf2f((u16)v[2]); xo = bf2f((u16)v[3]);
  o[2] = (short)f2bf((xe * c01.z - xo * s01.z) * sc);
  o[3] = (short)f2bf((xo * c01.w + xe * s01.w) * sc);
  xe = bf2f((u16)v[4]); xo = bf2f((u16)v[5]);
  o[4] = (short)f2bf((xe * c23.x - xo * s23.x) * sc);
  o[5] = (short)f2bf((xo * c23.y + xe * s23.y) * sc);
  xe = bf2f((u16)v[6]); xo = bf2f((u16)v[7]);
  o[6] = (short)f2bf((xe * c23.z - xo * s23.z) * sc);
  o[7] = (short)f2bf((xo * c23.w + xe * s23.w) * sc);
  *reinterpret_cast<short8*>(p) = o;
}

// ========== 8-phase 256x256 GEMM: C = A[M][Kst] @ BT[N][Kst]^T (+bias) ======
// 8 waves (2M x 4N), per-wave 128x64. K-half ring: A-ring 4x16KB + B-ring
// 4x16KB (128 KB). khalf H = 256 rows x 32k, XOR-swizzled (2-way free),
// staged pre-swizzled-source + linear dest. Sync invariant (the R10 fix):
// slot H is proven landed for ALL waves by the boundary {counted VMW;
// s_barrier} at the END of iteration H-1 — the wait always precedes a
// barrier that separates it from the reads. vmcnt never drains in steady
// state (8 in flight); tail 4 then 0.
// MODE 0: bf16+bias; 1: bf16+bias+GELU; 2: f32 partial, split-K via
// blockIdx.z (ks=0 -> C0, ks=1 -> C1; no bias).
template <int MODE>
__global__ __launch_bounds__(512) void gemm8p(const u16* __restrict__ A,
                                              const u16* __restrict__ BT,
                                              const float* __restrict__ bias,
                                              void* __restrict__ C0,
                                              void* __restrict__ C1,
                                              int Kstride, int KT, int ldc) {
  __shared__ float4 lds_v[8192];  // 131072 B
  char* lds = (char*)lds_v;
  int t = threadIdx.x;
  int w = t >> 6, l = t & 63, c = l & 15, g = l >> 4;
  int wm = w >> 2, wn = w & 3;
  int ks = blockIdx.z;
  size_t m0 = (size_t)blockIdx.y * 256, n0 = (size_t)blockIdx.x * 256;
  const u16* Ab = A + m0 * Kstride + (size_t)ks * KT * 64;
  const u16* Bb = BT + n0 * Kstride + (size_t)ks * KT * 64;
  int HMAX = 2 * KT - 1;

  f32x4 zero4 = {0.f, 0.f, 0.f, 0.f};
  f32x4 acc[8][4];
#pragma unroll
  for (int a = 0; a < 8; ++a)
#pragma unroll
    for (int b2 = 0; b2 < 4; ++b2) acc[a][b2] = zero4;

  // stage khalf HH (256 rows x 32k = 16 KB) into ring slot; 2 loads/thread.
  auto stg = [&](const u16* gbase, int HH, char* ring) {
    char* dst = ring + (HH & 3) * 16384;
    int koff = (HH >> 1) * 64 + (HH & 1) * 32;
#pragma unroll
    for (int j = 0; j < 2; ++j) {
      int u = j * 512 + t;
      int row = u >> 2;
      int kss = (u & 3) ^ ((row >> 1) & 3);
      const u16* src = gbase + (size_t)row * Kstride + koff + kss * 8;
      __builtin_amdgcn_global_load_lds(
          (const __attribute__((address_space(1))) unsigned int*)src,
          (__attribute__((address_space(3))) unsigned int*)(dst + u * 16), 16, 0, 0);
    }
  };
  // swizzled frag read: 16B at (row, kslot g)
  auto ldf = [&](const char* slot, int row) {
    return *reinterpret_cast<const short8*>(slot + row * 64 + ((g ^ ((row >> 1) & 3)) << 4));
  };

  // prologue: khalves 0,1,2 of A and B (12 loads/thread, issue order A0,B0,..)
  stg(Ab, 0, lds); stg(Bb, 0, lds + 65536);
  stg(Ab, 1, lds); stg(Bb, 1, lds + 65536);
  stg(Ab, 2, lds); stg(Bb, 2, lds + 65536);
  VMW(8);  // issued 12, need A0+B0 (4) -> allow 8
  __builtin_amdgcn_s_barrier();  // slot 0 landed for ALL waves

  for (int H = 0; H <= HMAX; ++H) {
    const char* Aslot = lds + (H & 3) * 16384;
    const char* Bslot = lds + 65536 + (H & 3) * 16384;
    bool sf = (H + 3 <= HMAX);
    short8 bv[4], av[4];

    // ---- even phase (A rows 0-63 of wave tile) ----
    if (sf) stg(Ab, H + 3, lds);  // writes slot (H-1)&3: sealed by boundary barrier
#pragma unroll
    for (int nj = 0; nj < 4; ++nj) bv[nj] = ldf(Bslot, wn * 64 + 16 * nj + c);
#pragma unroll
    for (int i = 0; i < 4; ++i) av[i] = ldf(Aslot, wm * 128 + 16 * i + c);
    __builtin_amdgcn_s_setprio(1);
#pragma unroll
    for (int i = 0; i < 4; ++i)
#pragma unroll
      for (int nj = 0; nj < 4; ++nj)
        acc[i][nj] = __builtin_amdgcn_mfma_f32_16x16x32_bf16(av[i], bv[nj], acc[i][nj], 0, 0, 0);
    __builtin_amdgcn_s_setprio(0);
    __builtin_amdgcn_s_barrier();  // phase lockstep

    // ---- odd phase (A rows 64-127) ----
    if (sf) stg(Bb, H + 3, lds + 65536);
#pragma unroll
    for (int i = 0; i < 4; ++i) av[i] = ldf(Aslot, wm * 128 + 64 + 16 * i + c);
    __builtin_amdgcn_s_setprio(1);
#pragma unroll
    for (int i = 0; i < 4; ++i)
#pragma unroll
      for (int nj = 0; nj < 4; ++nj)
        acc[4 + i][nj] = __builtin_amdgcn_mfma_f32_16x16x32_bf16(av[i], bv[nj], acc[4 + i][nj], 0, 0, 0);
    __builtin_amdgcn_s_setprio(0);

    // ---- boundary: prove slot H+1 landed for all waves ----
    if (H < HMAX) {
      if (sf) { VMW(8); }                     // 2 khalf-pairs in flight
      else if (H + 2 <= HMAX) { VMW(4); }     // 1 pair in flight
      else { VMW(0); }
      __builtin_amdgcn_s_barrier();
    }
  }

  // ---- epilogue ----
#pragma unroll
  for (int nj = 0; nj < 4; ++nj) {
    int col = (int)n0 + wn * 64 + 16 * nj + c;
    float bvv = (MODE == 2) ? 0.f : bias[col];
#pragma unroll
    for (int mi = 0; mi < 8; ++mi) {
      size_t rbase = m0 + wm * 128 + 16 * mi + 4 * g;
#pragma unroll
      for (int r = 0; r < 4; ++r) {
        float f = acc[mi][nj][r] + bvv;
        if (MODE == 1) f = 0.5f * f * (1.0f + erff(f * 0.70710678f));
        size_t oidx = (rbase + r) * (size_t)ldc + col;
        if (MODE == 2) {
          float* dst = (float*)(ks ? C1 : C0);
          dst[oidx] = f;
        } else {
          ((u16*)C0)[oidx] = f2bf(f);
        }
      }
    }
  }
}

// ---- split-K reduce: out = out + P0 + bias (f32, 8192x1024) ----
__global__ __launch_bounds__(256) void redadd(float* __restrict__ out,
                                              const float* __restrict__ p0,
                                              const float* __restrict__ bias) {
  size_t i = ((size_t)blockIdx.x * 256 + threadIdx.x) * 4;
  float4 a = *reinterpret_cast<const float4*>(out + i);
  float4 b = *reinterpret_cast<const float4*>(p0 + i);
  float4 bb = *reinterpret_cast<const float4*>(bias + (i & 1023));
  float4 o;
  o.x = a.x + b.x + bb.x;
  o.y = a.y + b.y + bb.y;
  o.z = a.z + b.z + bb.z;
  o.w = a.w + b.w + bb.w;
  *reinterpret_cast<float4*>(out + i) = o;
}

// ---------------- sliding-window causal attention ----------------
// 1 wave per 32-query tile, no barriers. grid = B*NH*(S/32) = 4096, block = 64.
// Q pre-scaled by 0.125. K frags direct global; V frags direct from vT.
__global__ __launch_bounds__(64, 4) void attn_kernel(const u16* __restrict__ qkv,
                                                     const u16* __restrict__ vT,
                                                     u16* __restrict__ comb) {
  int bid = blockIdx.x;
  int swz = ((bid & 7) << 9) + (bid >> 3);  // 4096/8 = 512 per XCD
  int qt = swz & 127, h = (swz >> 7) & 15, b = swz >> 11;
  int l = threadIdx.x, c = l & 15, g = l >> 4;
  int q0 = qt * 32;
  const u16* qb = qkv + (size_t)b * 4096 * 3072 + h * 64;
  const u16* kb = qb + 1024;
  const u16* vt = vT + (size_t)(b * 16 + h) * 64 * 4096;
  __shared__ u16 Pl[32 * 72];

  short8 qf[2][2];
#pragma unroll
  for (int mi = 0; mi < 2; ++mi)
#pragma unroll
    for (int kk = 0; kk < 2; ++kk)
      qf[mi][kk] = *reinterpret_cast<const short8*>(
          qb + (size_t)(q0 + 16 * mi + c) * 3072 + 32 * kk + 8 * g);

  f32x4 zero4 = {0.f, 0.f, 0.f, 0.f};
  f32x4 o[2][4];
  float mr[2][4], lr[2][4];
#pragma unroll
  for (int a = 0; a < 2; ++a)
#pragma unroll
    for (int d2 = 0; d2 < 4; ++d2) {
      o[a][d2] = zero4;
      mr[a][d2] = -1e30f;
      lr[a][d2] = 0.f;
    }

  int t_lo = (q0 >= 480) ? ((q0 - 480) >> 6) : 0;
  int t_hi = (q0 + 31) >> 6;
  for (int tt = t_lo; tt <= t_hi; ++tt) {
    int kt0 = tt * 64;
    f32x4 s[2][4];
#pragma unroll
    for (int a = 0; a < 2; ++a)
#pragma unroll
      for (int d2 = 0; d2 < 4; ++d2) s[a][d2] = zero4;

#pragma unroll
    for (int kk = 0; kk < 2; ++kk) {
      short8 kf[4];
#pragma unroll
      for (int nj = 0; nj < 4; ++nj)
        kf[nj] = *reinterpret_cast<const short8*>(
            kb + (size_t)(kt0 + 16 * nj + c) * 3072 + 32 * kk + 8 * g);
#pragma unroll
      for (int mi = 0; mi < 2; ++mi)
#pragma unroll
        for (int nj = 0; nj < 4; ++nj)
          s[mi][nj] = __builtin_amdgcn_mfma_f32_16x16x32_bf16(qf[mi][kk], kf[nj], s[mi][nj], 0, 0, 0);
    }

    // mask only on the boundary tiles (wave-uniform branch)
    bool mc = (tt == t_hi), mw = (tt == t_lo);
    if (mc | mw) {
#pragma unroll
      for (int mi = 0; mi < 2; ++mi)
#pragma unroll
        for (int nj = 0; nj < 4; ++nj)
#pragma unroll
          for (int r = 0; r < 4; ++r) {
            int qg = q0 + 16 * mi + 4 * g + r;
            int kg = kt0 + 16 * nj + c;
            if ((mc && kg > qg) || (mw && qg - kg >= 512)) s[mi][nj][r] = -1e30f;
          }
    }

#pragma unroll
    for (int mi = 0; mi < 2; ++mi)
#pragma unroll
      for (int r = 0; r < 4; ++r) {
        float tm = fmaxf(fmaxf(s[mi][0][r], s[mi][1][r]), fmaxf(s[mi][2][r], s[mi][3][r]));
        tm = redmax16(tm);
        float mn = fmaxf(mr[mi][r], tm);
        float a = __expf(mr[mi][r] - mn);
        mr[mi][r] = mn;
        float rs = 0.f;
        u16* pp = &Pl[(16 * mi + 4 * g + r) * 72 + c];
#pragma unroll
        for (int nj = 0; nj < 4; ++nj) {
          float p = __expf(s[mi][nj][r] - mn);
          rs += p;
          pp[16 * nj] = f2bf(p);  // natural k order, imm-offset ds_write_b16
        }
        rs = redsum16(rs);
        lr[mi][r] = lr[mi][r] * a + rs;
#pragma unroll
        for (int dj = 0; dj < 4; ++dj) o[mi][dj][r] *= a;
      }

    // PV: A-frag from Pl (natural order), B-frag = k-contiguous rows of vT
#pragma unroll
    for (int kk = 0; kk < 2; ++kk) {
      short8 pa[2];
#pragma unroll
      for (int mi = 0; mi < 2; ++mi)
        pa[mi] = *reinterpret_cast<const short8*>(&Pl[(16 * mi + c) * 72 + 32 * kk + 8 * g]);
      short8 bv[4];
#pragma unroll
      for (int dj = 0; dj < 4; ++dj)
        bv[dj] = *reinterpret_cast<const short8*>(
            vt + (size_t)(16 * dj + c) * 4096 + kt0 + 32 * kk + 8 * g);
#pragma unroll
      for (int mi = 0; mi < 2; ++mi)
#pragma unroll
        for (int dj = 0; dj < 4; ++dj)
          o[mi][dj] = __builtin_amdgcn_mfma_f32_16x16x32_bf16(pa[mi], bv[dj], o[mi][dj], 0, 0, 0);
    }
  }

  u16* ob = comb + (size_t)(b * 4096 + q0) * 5120 + h * 64;
#pragma unroll
  for (int mi = 0; mi < 2; ++mi)
#pragma unroll
    for (int r = 0; r < 4; ++r) {
      float inv = __builtin_amdgcn_rcpf(lr[mi][r]);
#pragma unroll
      for (int dj = 0; dj < 4; ++dj)
        ob[(size_t)(16 * mi + 4 * g + r) * 5120 + 16 * dj + c] = f2bf(o[mi][dj][r] * inv);
    }
}

// ---------------- launch ----------------
extern "C" void kernel_launch(void* const* d_in, const int* in_sizes, int n_in,
                              void* d_out, int out_size, void* d_ws, size_t ws_size,
                              hipStream_t stream) {
  const float* x = (const float*)d_in[0];
  const float* sinp = (const float*)d_in[1];
  const float* cosp = (const float*)d_in[2];
  const float* norm_w = (const float*)d_in[3];
  const float* w_qkv = (const float*)d_in[4];
  const float* b_qkv = (const float*)d_in[5];
  const float* w_in = (const float*)d_in[6];
  const float* b_in = (const float*)d_in[7];
  const float* w_out = (const float*)d_in[8];
  const float* b_out = (const float*)d_in[9];
  float* out = (float*)d_out;

  char* ws = (char*)d_ws;
  u16* xn = (u16*)(ws);                        // 8192*1024*2      = 16,777,216
  u16* vT = (u16*)(ws);                        // aliases xn (xn dead after FF gemm)
  u16* qkv = (u16*)(ws + 16777216);            // 8192*3072*2      = 50,331,648
  float* P0 = (float*)(ws + 16777216);         // split-K partial; aliases qkv (dead after attn)
  u16* comb = (u16*)(ws + 67108864);           // 8192*5120*2      = 83,886,080
  u16* wqkvT = (u16*)(ws + 150994944);         // 3072*1024*2      = 6,291,456
  u16* winT = (u16*)(ws + 157286400);          // 4096*1024*2      = 8,388,608
  u16* woutT = (u16*)(ws + 165675008);         // 1024*5120*2      = 10,485,760

  transpose_f32_bf16<<<dim3(3072 / 32, 1024 / 32), 256, 0, stream>>>(w_qkv, wqkvT, 1024, 3072);
  transpose_f32_bf16<<<dim3(4096 / 32, 1024 / 32), 256, 0, stream>>>(w_in, winT, 1024, 4096);
  transpose_f32_bf16<<<dim3(1024 / 32, 5120 / 32), 256, 0, stream>>>(w_out, woutT, 5120, 1024);

  rmsnorm_kernel<<<8192, 256, 0, stream>>>(x, norm_w, xn);

  // qkv = xn @ w_qkv + b_qkv   (bf16 out)  grid 12x32
  gemm8p<0><<<dim3(12, 32, 1), 512, 0, stream>>>(xn, wqkvT, b_qkv, qkv, nullptr, 1024, 16, 3072);

  rope_kernel<<<8192, 256, 0, stream>>>(qkv, sinp, cosp);

  // ff = gelu(xn @ w_in + b_in) -> comb cols [1024, 5120)  grid 16x32
  gemm8p<1><<<dim3(16, 32, 1), 512, 0, stream>>>(xn, winT, b_in, comb + 1024, nullptr, 1024, 16, 5120);

  // vT[b,h][d][s] = V  (into xn's region; xn dead after FF gemm)
  transpose_v<<<dim3(128, 2, 32), 256, 0, stream>>>(qkv, vT);

  attn_kernel<<<4096, 64, 0, stream>>>(qkv, vT, comb);

  // out-partials = comb @ w_out  (f32, split-K=2; qkv region dead -> P0)
  gemm8p<2><<<dim3(4, 32, 2), 512, 0, stream>>>(comb, woutT, nullptr, P0, out, 5120, 40, 1024);

  // out = out + P0 + b_out
  redadd<<<8192, 256, 0, stream>>>(out, P0, b_out);
}